// Round 5
// baseline (104.170 us; speedup 1.0000x reference)
//
#include <hip/hip_runtime.h>

// Problem: B=2, T=2048, C=1024, H=16, D=64
// qkv = x @ w + b ; q,k,v split; att = relu(causal(q k^T / 8)); y = att @ v
// Output fp32 [B,T,C]. Compute in bf16 MFMA with fp32 accum.

typedef unsigned int u32;
typedef float  f32x4  __attribute__((ext_vector_type(4)));
typedef float  f32x16 __attribute__((ext_vector_type(16)));
typedef short  s16x8  __attribute__((ext_vector_type(8)));

#define MFMA_BF16(a, b, c) __builtin_amdgcn_mfma_f32_16x16x32_bf16((a), (b), (c), 0, 0, 0)
#define MFMA32(a, b, c)    __builtin_amdgcn_mfma_f32_32x32x16_bf16((a), (b), (c), 0, 0, 0)

#define GLOAD16(g, l)                                                        \
  __builtin_amdgcn_global_load_lds(                                          \
      (__attribute__((address_space(1))) void*)(g),                          \
      (__attribute__((address_space(3))) void*)(l), 16, 0, 0)

__device__ __forceinline__ unsigned short f2bf(float f) {
  union { float f; u32 u; } x; x.f = f;
  u32 r = (x.u + 0x7fffu + ((x.u >> 16) & 1u)) >> 16;
  return (unsigned short)r;
}

// HW packed f32->bf16 (round-to-nearest-even)
static __device__ __forceinline__ u32 cvtpk1(float a, float b) {
  u32 r;
  asm("v_cvt_pk_bf16_f32 %0, %1, %2" : "=v"(r) : "v"(a), "v"(b));
  return r;
}
// swap lanes[32:63] of a with lanes[0:31] of b
static __device__ __forceinline__ void pl32swap(u32& a, u32& b) {
  asm("v_permlane32_swap_b32 %0, %1" : "+v"(a), "+v"(b));
}

// ---------------- kernel 1: x fp32 -> bf16 ----------------
__global__ void cvt_x_kernel(const float* __restrict__ x, unsigned short* __restrict__ xb) {
  int i = blockIdx.x * 256 + threadIdx.x;
  float4 v = ((const float4*)x)[i];
  ushort4 o;
  o.x = f2bf(v.x); o.y = f2bf(v.y); o.z = f2bf(v.z); o.w = f2bf(v.w);
  ((ushort4*)xb)[i] = o;
}

// ---------------- kernel 2: w [1024][3072] fp32 -> wT [3072][1024] bf16 ----
__global__ void transpose_w_kernel(const float* __restrict__ w, unsigned short* __restrict__ wT) {
  __shared__ unsigned short TL[64][72];
  const int tid = threadIdx.x;
  const int c0 = blockIdx.x * 64;
  const int r0 = blockIdx.y * 64;
#pragma unroll
  for (int p = 0; p < 4; ++p) {
    int r = p * 16 + (tid >> 4);
    int c = (tid & 15) * 4;
    float4 v = *(const float4*)&w[(size_t)(r0 + r) * 3072 + c0 + c];
    TL[c + 0][r] = f2bf(v.x);
    TL[c + 1][r] = f2bf(v.y);
    TL[c + 2][r] = f2bf(v.z);
    TL[c + 3][r] = f2bf(v.w);
  }
  __syncthreads();
#pragma unroll
  for (int p = 0; p < 4; ++p) {
    int c = p * 16 + (tid >> 4);
    int r = (tid & 15) * 4;
    ushort4 o;
    o.x = TL[c][r + 0]; o.y = TL[c][r + 1]; o.z = TL[c][r + 2]; o.w = TL[c][r + 3];
    *(ushort4*)&wT[(size_t)(c0 + c) * 1024 + r0 + r] = o;
  }
}

// ---------------- kernel 3: GEMM qkv = xb @ wT^T + bias ------------------
// bn<8: q (pre-scaled 1/8) -> Cq[.][0:1024); bn in [8,16): k -> Cq[.][1024:2048)
// bn>=16: v written TRANSPOSED to Vt [B][H][D][T] (ushort4, t-contiguous).
__global__ __launch_bounds__(256, 2) void gemm_qkv_kernel(
    const unsigned short* __restrict__ A, const unsigned short* __restrict__ Bt,
    const float* __restrict__ bias, unsigned short* __restrict__ Cq,
    unsigned short* __restrict__ Vt) {
  __shared__ __align__(16) unsigned short As[128 * 32];
  __shared__ __align__(16) unsigned short Bs[128 * 32];
  const int tid = threadIdx.x;
  const int lane = tid & 63, wid = tid >> 6;
  const int wr = wid >> 1, wc = wid & 1;
  const int g = lane >> 4, lm = lane & 15;
  const int bm = blockIdx.y, bn = blockIdx.x;

  const unsigned short* gA = A  + (size_t)(bm * 128 + wid * 32 + (lane >> 2)) * 1024 + (lane & 3) * 8;
  const unsigned short* gB = Bt + (size_t)(bn * 128 + wid * 32 + (lane >> 2)) * 1024 + (lane & 3) * 8;
  unsigned short* lA0 = &As[wid * 1024];
  unsigned short* lA1 = &As[wid * 1024 + 512];
  unsigned short* lB0 = &Bs[wid * 1024];
  unsigned short* lB1 = &Bs[wid * 1024 + 512];

  f32x4 acc[4][4] = {};

  for (int kt = 0; kt < 32; ++kt) {
    __syncthreads();
    const unsigned short* a0 = gA + kt * 32;
    const unsigned short* b0 = gB + kt * 32;
    GLOAD16(a0,             lA0);
    GLOAD16(a0 + 16 * 1024, lA1);
    GLOAD16(b0,             lB0);
    GLOAD16(b0 + 16 * 1024, lB1);
    __syncthreads();

    s16x8 af[4], bf[4];
#pragma unroll
    for (int m = 0; m < 4; ++m)
      af[m] = *(const s16x8*)&As[(wr * 64 + m * 16 + lm) * 32 + g * 8];
#pragma unroll
    for (int n = 0; n < 4; ++n)
      bf[n] = *(const s16x8*)&Bs[(wc * 64 + n * 16 + lm) * 32 + g * 8];
#pragma unroll
    for (int m = 0; m < 4; ++m)
#pragma unroll
      for (int n = 0; n < 4; ++n)
        acc[m][n] = MFMA_BF16(af[m], bf[n], acc[m][n]);
  }

  if (bn < 16) {
    const float qs = (bn < 8) ? 0.125f : 1.0f;   // fold attention scale into q
#pragma unroll
    for (int m = 0; m < 4; ++m) {
      const int row = bm * 128 + wr * 64 + m * 16 + g * 4;
#pragma unroll
      for (int n = 0; n < 4; ++n) {
        const int col = bn * 128 + wc * 64 + n * 16 + lm;
        const float bv = bias[col];
#pragma unroll
        for (int r = 0; r < 4; ++r)
          Cq[(size_t)(row + r) * 2048 + col] = f2bf((acc[m][n][r] + bv) * qs);
      }
    }
  } else {
#pragma unroll
    for (int m = 0; m < 4; ++m) {
      const int row = bm * 128 + wr * 64 + m * 16 + g * 4;   // b*2048 + t
      const int bb = row >> 11, tt = row & 2047;
#pragma unroll
      for (int n = 0; n < 4; ++n) {
        const int col = bn * 128 + wc * 64 + n * 16 + lm;
        const int cv = col - 2048;                           // h*64 + d
        const float bv = bias[col];
        ushort4 o;
#pragma unroll
        for (int r = 0; r < 4; ++r)
          ((unsigned short*)&o)[r] = f2bf(acc[m][n][r] + bv);
        *(ushort4*)&Vt[((size_t)(bb * 1024 + cv)) * 2048 + tt] = o;
      }
    }
  }
}

// ---------------- kernel 4: attention v5 (8-warp 32x32 structure) ---------
// Per (b,h): 144 units (64-s KV steps) over 8 q-tiles of 256 rows (tile qb
// has 4qb+4 units); 16 blocks x 9 units, XCD-pinned so each XCD serves 4
// (b,h) pairs from its L2. 8 warps x 32 q-rows. QK^T = mfma32(K,Q) -> S^T;
// relu/mask; cvt_pk + permlane32_swap -> PA frags; PV = mfma32(PA, V).
// K/V tiles in LDS in fragment order: 16 groups x (256+8) ushorts (padded),
// so every frag read is two contiguous 512B ds_read_b128 runs.
__global__ __launch_bounds__(512, 4) void attn_kernel(
    const unsigned short* __restrict__ qkv, const unsigned short* __restrict__ Vt,
    float* __restrict__ out) {
  __shared__ __align__(16) unsigned short Ks[2][4224];
  __shared__ __align__(16) unsigned short Vs[2][4224];
  const int tid = threadIdx.x, lane = tid & 63, wid = tid >> 6;  // wid 0..7
  const int hi = lane >> 5, li = lane & 31;
  const int bid = blockIdx.x;
  const int xcd = bid & 7, slot = bid >> 3;
  const int bh = xcd * 4 + (slot >> 4);      // 0..31
  const int kq = slot & 15;                  // 0..15 queue block
  const int b = bh >> 4, h = bh & 15;
  const size_t qbase = (size_t)(b * 2048) * 2048 + h * 64;
  const size_t kbase = qbase + 1024;
  const size_t vtbase = (size_t)(b * 1024 + h * 64) * 2048;

  // staging: thread -> row r_ (K: s, V: d), 8-elem chunk sj; frag-order LDS
  const int r_ = tid >> 3, sj = tid & 7;
  const unsigned lw = (unsigned)(((r_ >> 5) * 8 + sj) * 264 + (r_ & 31) * 8);

  // locate start unit: base(qb) = 2*qb*(qb+1), tile qb has 4qb+4 units
  const int u0 = kq * 9;
  int qb = 0;
  while (2 * (qb + 1) * (qb + 2) <= u0) ++qb;
  int st = u0 - 2 * qb * (qb + 1);

  int qrow0 = qb * 256 + wid * 32;
  s16x8 qf0, qf1, qf2, qf3;
  {
    const unsigned short* qp = &qkv[qbase + (size_t)(qrow0 + li) * 2048 + hi * 8];
    qf0 = *(const s16x8*)(qp);      qf1 = *(const s16x8*)(qp + 16);
    qf2 = *(const s16x8*)(qp + 32); qf3 = *(const s16x8*)(qp + 48);
  }
  f32x16 yacc0 = {}, yacc1 = {};

  // stage first unit into buffer 0
  s16x8 kr = *(const s16x8*)&qkv[kbase + (size_t)(st * 64 + r_) * 2048 + sj * 8];
  s16x8 vr = *(const s16x8*)&Vt[vtbase + (size_t)r_ * 2048 + st * 64 + sj * 8];
  *(s16x8*)&Ks[0][lw] = kr;
  *(s16x8*)&Vs[0][lw] = vr;
  __syncthreads();

  int cur = 0;
  for (int i = 0; i < 9; ++i) {
    int qbN = qb, stN = st + 1;
    if (stN == 4 * qb + 4) { qbN = qb + 1; stN = 0; }
    const bool pf = (i < 8);
    if (pf) {                                // prefetch next unit (K/V agnostic of qb)
      kr = *(const s16x8*)&qkv[kbase + (size_t)(stN * 64 + r_) * 2048 + sj * 8];
      vr = *(const s16x8*)&Vt[vtbase + (size_t)r_ * 2048 + stN * 64 + sj * 8];
    }
    const int s0 = st * 64;
    if (s0 <= qrow0 + 31) {                  // warp has unmasked work this step
      const unsigned short* Kc = Ks[cur];
      const unsigned short* Vc = Vs[cur];
      const bool dm = (s0 + 63 > qrow0);     // step crosses the diagonal
      const int qg = qrow0 + li;
      __builtin_amdgcn_s_setprio(1);
#pragma unroll
      for (int sb2 = 0; sb2 < 2; ++sb2) {
        f32x16 sacc = {};
        {
          const unsigned short* kp = &Kc[(sb2 * 8 + hi) * 264 + li * 8];
          sacc = MFMA32(*(const s16x8*)(kp),           qf0, sacc);
          sacc = MFMA32(*(const s16x8*)(kp + 2 * 264), qf1, sacc);
          sacc = MFMA32(*(const s16x8*)(kp + 4 * 264), qf2, sacc);
          sacc = MFMA32(*(const s16x8*)(kp + 6 * 264), qf3, sacc);
        }
        float pr[16];
#pragma unroll
        for (int r = 0; r < 16; ++r) {
          float v = sacc[r] > 0.f ? sacc[r] : 0.f;
          if (dm) {
            const int sg = s0 + sb2 * 32 + (r & 3) + 8 * (r >> 2) + 4 * hi;
            if (sg > qg) v = 0.f;
          }
          pr[r] = v;
        }
#pragma unroll
        for (int hh = 0; hh < 2; ++hh) {
          u32 a0 = cvtpk1(pr[8 * hh + 0], pr[8 * hh + 1]);
          u32 b0 = cvtpk1(pr[8 * hh + 4], pr[8 * hh + 5]);
          u32 a1 = cvtpk1(pr[8 * hh + 2], pr[8 * hh + 3]);
          u32 b1 = cvtpk1(pr[8 * hh + 6], pr[8 * hh + 7]);
          pl32swap(a0, b0);
          pl32swap(a1, b1);
          union { s16x8 v; u32 w[4]; } pa;
          pa.w[0] = a0; pa.w[1] = a1; pa.w[2] = b0; pa.w[3] = b1;
          const int sc = sb2 * 2 + hh;
          const unsigned short* vp = &Vc[(sc * 2 + hi) * 264 + li * 8];
          yacc0 = MFMA32(pa.v, *(const s16x8*)(vp), yacc0);
          yacc1 = MFMA32(pa.v, *(const s16x8*)(vp + 8 * 264), yacc1);
        }
      }
      __builtin_amdgcn_s_setprio(0);
    }
    if (pf) {                                // write prefetched tile to other buf
      *(s16x8*)&Ks[cur ^ 1][lw] = kr;
      *(s16x8*)&Vs[cur ^ 1][lw] = vr;
    }
    if (qbN != qb || i == 8) {               // flush (partial) q-tile
      const size_t obase = (size_t)(b * 2048) * 1024 + h * 64;
#pragma unroll
      for (int r = 0; r < 16; ++r) {
        const int q = qrow0 + (r & 3) + 8 * (r >> 2) + 4 * hi;
        float* op = &out[obase + (size_t)q * 1024 + li];
        atomicAdd(op, yacc0[r]);
        atomicAdd(op + 32, yacc1[r]);
      }
      if (pf && qbN != qb) {
        qrow0 = qbN * 256 + wid * 32;
        const unsigned short* qp = &qkv[qbase + (size_t)(qrow0 + li) * 2048 + hi * 8];
        qf0 = *(const s16x8*)(qp);      qf1 = *(const s16x8*)(qp + 16);
        qf2 = *(const s16x8*)(qp + 32); qf3 = *(const s16x8*)(qp + 48);
        yacc0 = (f32x16){}; yacc1 = (f32x16){};
      }
    }
    __syncthreads();
    cur ^= 1; qb = qbN; st = stN;
  }
}

extern "C" void kernel_launch(void* const* d_in, const int* in_sizes, int n_in,
                              void* d_out, int out_size, void* d_ws, size_t ws_size,
                              hipStream_t stream) {
  const float* x    = (const float*)d_in[0];
  const float* w    = (const float*)d_in[1];
  const float* bias = (const float*)d_in[2];
  float* out = (float*)d_out;

  unsigned short* xb  = (unsigned short*)d_ws;            // 4096*1024 elems
  unsigned short* wT  = xb  + (size_t)4096 * 1024;        // 3072*1024
  unsigned short* qkv = wT  + (size_t)3072 * 1024;        // 4096*2048 (q|k)
  unsigned short* Vt  = qkv + (size_t)4096 * 2048;        // 1024*2048*2 (v^T)

  hipMemsetAsync(d_out, 0, (size_t)out_size * sizeof(float), stream);
  cvt_x_kernel<<<4096, 256, 0, stream>>>(x, xb);
  transpose_w_kernel<<<dim3(48, 16), 256, 0, stream>>>(w, wT);
  gemm_qkv_kernel<<<dim3(24, 32), 256, 0, stream>>>(xb, wT, bias, qkv, Vt);
  attn_kernel<<<512, 512, 0, stream>>>(qkv, Vt, out);
}

// Round 6
// 98.293 us; speedup vs baseline: 1.0598x; 1.0598x over previous
//
#include <hip/hip_runtime.h>

// Problem: B=2, T=2048, C=1024, H=16, D=64
// qkv = x @ w + b ; q,k,v split; att = relu(causal(q k^T / 8)); y = att @ v
// Output fp32 [B,T,C]. Compute in bf16 MFMA with fp32 accum.

typedef unsigned int u32;
typedef float  f32x4  __attribute__((ext_vector_type(4)));
typedef float  f32x16 __attribute__((ext_vector_type(16)));
typedef short  s16x8  __attribute__((ext_vector_type(8)));

#define MFMA_BF16(a, b, c) __builtin_amdgcn_mfma_f32_16x16x32_bf16((a), (b), (c), 0, 0, 0)
#define MFMA32(a, b, c)    __builtin_amdgcn_mfma_f32_32x32x16_bf16((a), (b), (c), 0, 0, 0)

#define GLOAD16(g, l)                                                        \
  __builtin_amdgcn_global_load_lds(                                          \
      (__attribute__((address_space(1))) void*)(g),                          \
      (__attribute__((address_space(3))) void*)(l), 16, 0, 0)

__device__ __forceinline__ unsigned short f2bf(float f) {
  union { float f; u32 u; } x; x.f = f;
  u32 r = (x.u + 0x7fffu + ((x.u >> 16) & 1u)) >> 16;
  return (unsigned short)r;
}

// HW packed f32->bf16 (round-to-nearest-even)
static __device__ __forceinline__ u32 cvtpk1(float a, float b) {
  u32 r;
  asm("v_cvt_pk_bf16_f32 %0, %1, %2" : "=v"(r) : "v"(a), "v"(b));
  return r;
}
// swap lanes[32:63] of a with lanes[0:31] of b
static __device__ __forceinline__ void pl32swap(u32& a, u32& b) {
  asm("v_permlane32_swap_b32 %0, %1" : "+v"(a), "+v"(b));
}

// ---------------- kernel 1: x fp32 -> bf16 ----------------
__global__ void cvt_x_kernel(const float* __restrict__ x, unsigned short* __restrict__ xb) {
  int i = blockIdx.x * 256 + threadIdx.x;
  float4 v = ((const float4*)x)[i];
  ushort4 o;
  o.x = f2bf(v.x); o.y = f2bf(v.y); o.z = f2bf(v.z); o.w = f2bf(v.w);
  ((ushort4*)xb)[i] = o;
}

// ---------------- kernel 2: w [1024][3072] fp32 -> wT [3072][1024] bf16 ----
__global__ void transpose_w_kernel(const float* __restrict__ w, unsigned short* __restrict__ wT) {
  __shared__ unsigned short TL[64][72];
  const int tid = threadIdx.x;
  const int c0 = blockIdx.x * 64;
  const int r0 = blockIdx.y * 64;
#pragma unroll
  for (int p = 0; p < 4; ++p) {
    int r = p * 16 + (tid >> 4);
    int c = (tid & 15) * 4;
    float4 v = *(const float4*)&w[(size_t)(r0 + r) * 3072 + c0 + c];
    TL[c + 0][r] = f2bf(v.x);
    TL[c + 1][r] = f2bf(v.y);
    TL[c + 2][r] = f2bf(v.z);
    TL[c + 3][r] = f2bf(v.w);
  }
  __syncthreads();
#pragma unroll
  for (int p = 0; p < 4; ++p) {
    int c = p * 16 + (tid >> 4);
    int r = (tid & 15) * 4;
    ushort4 o;
    o.x = TL[c][r + 0]; o.y = TL[c][r + 1]; o.z = TL[c][r + 2]; o.w = TL[c][r + 3];
    *(ushort4*)&wT[(size_t)(c0 + c) * 1024 + r0 + r] = o;
  }
}

// ---------------- kernel 3: GEMM qkv = xb @ wT^T + bias ------------------
// bn<8: q (pre-scaled 1/8) -> Cq[.][0:1024); bn in [8,16): k -> Cq[.][1024:2048)
// bn>=16: v transposed via LDS -> Vt [B][H*64=1024 d][T] with coalesced stores.
// 1-D grid 768, XCD-swizzled: xcd = bid&7 owns 4 bm-panels (A L2-resident).
__global__ __launch_bounds__(256, 3) void gemm_qkv_kernel(
    const unsigned short* __restrict__ A, const unsigned short* __restrict__ Bt,
    const float* __restrict__ bias, unsigned short* __restrict__ Cq,
    unsigned short* __restrict__ Vt) {
  __shared__ __align__(16) unsigned short SM[8448];   // As | Bs, reused as TL
  unsigned short* As = SM;
  unsigned short* Bs = SM + 4096;
  const int tid = threadIdx.x;
  const int lane = tid & 63, wid = tid >> 6;
  const int wr = wid >> 1, wc = wid & 1;
  const int g = lane >> 4, lm = lane & 15;
  const int bid = blockIdx.x;
  const int xcd = bid & 7, wl = bid >> 3;              // wl 0..95
  const int bn = wl % 24;
  const int bm = xcd * 4 + wl / 24;

  const unsigned short* gA = A  + (size_t)(bm * 128 + wid * 32 + (lane >> 2)) * 1024 + (lane & 3) * 8;
  const unsigned short* gB = Bt + (size_t)(bn * 128 + wid * 32 + (lane >> 2)) * 1024 + (lane & 3) * 8;
  unsigned short* lA0 = &As[wid * 1024];
  unsigned short* lA1 = &As[wid * 1024 + 512];
  unsigned short* lB0 = &Bs[wid * 1024];
  unsigned short* lB1 = &Bs[wid * 1024 + 512];

  f32x4 acc[4][4] = {};

  for (int kt = 0; kt < 32; ++kt) {
    __syncthreads();
    const unsigned short* a0 = gA + kt * 32;
    const unsigned short* b0 = gB + kt * 32;
    GLOAD16(a0,             lA0);
    GLOAD16(a0 + 16 * 1024, lA1);
    GLOAD16(b0,             lB0);
    GLOAD16(b0 + 16 * 1024, lB1);
    __syncthreads();

    s16x8 af[4], bf[4];
#pragma unroll
    for (int m = 0; m < 4; ++m)
      af[m] = *(const s16x8*)&As[(wr * 64 + m * 16 + lm) * 32 + g * 8];
#pragma unroll
    for (int n = 0; n < 4; ++n)
      bf[n] = *(const s16x8*)&Bs[(wc * 64 + n * 16 + lm) * 32 + g * 8];
#pragma unroll
    for (int m = 0; m < 4; ++m)
#pragma unroll
      for (int n = 0; n < 4; ++n)
        acc[m][n] = MFMA_BF16(af[m], bf[n], acc[m][n]);
  }

  if (bn < 16) {
    const float qs = (bn < 8) ? 0.125f : 1.0f;   // fold attention scale into q
#pragma unroll
    for (int m = 0; m < 4; ++m) {
      const int row = bm * 128 + wr * 64 + m * 16 + g * 4;
#pragma unroll
      for (int n = 0; n < 4; ++n) {
        const int col = bn * 128 + wc * 64 + n * 16 + lm;
        const float bv = bias[col];
#pragma unroll
        for (int r = 0; r < 4; ++r)
          Cq[(size_t)(row + r) * 2048 + col] = f2bf((acc[m][n][r] + bv) * qs);
      }
    }
  } else {
    // V: transpose 128x128 C-tile via LDS (two 64-col passes), coalesced store
    unsigned short* TL = SM;                     // [64][132]
    const int bb = bm >> 4, tt0 = (bm & 15) * 128;
    __syncthreads();                             // As/Bs reads done
#pragma unroll
    for (int p = 0; p < 2; ++p) {
      if (wc == p) {
#pragma unroll
        for (int m = 0; m < 4; ++m) {
          const int r = wr * 64 + m * 16 + g * 4;
#pragma unroll
          for (int n = 0; n < 4; ++n) {
            const int c = n * 16 + lm;
            const float bv = bias[bn * 128 + p * 64 + c];
            ushort4 o;
#pragma unroll
            for (int r2 = 0; r2 < 4; ++r2)
              ((unsigned short*)&o)[r2] = f2bf(acc[m][n][r2] + bv);
            *(ushort4*)&TL[c * 132 + r] = o;
          }
        }
      }
      __syncthreads();
      const int cl = tid >> 2;                   // 0..63 local col
      const int ch = (tid & 3) * 32;
      const int cv = bn * 128 + p * 64 + cl - 2048;   // global d-row in Vt
      unsigned short* vrow = &Vt[((size_t)(bb * 1024 + cv)) * 2048 + tt0 + ch];
#pragma unroll
      for (int k2 = 0; k2 < 4; ++k2)
        *(s16x8*)&vrow[k2 * 8] = *(const s16x8*)&TL[cl * 132 + ch + k2 * 8];
      __syncthreads();
    }
  }
}

// ---------------- kernel 4: attention v6 ----------------------------------
// Exclusive balanced pairs: block owns 64-row q-tiles (31-j, j), processed
// sequentially -> uniform 33 KV-steps. 512 blocks (2/CU), 2 warps x 32 rows.
// QK^T = mfma32(K,Q) swapped; P via cvt_pk + permlane32_swap; PV = mfma32.
// Frag-order LDS (zero bank conflicts), double-buffered, T14 prefetch,
// one barrier/step. Plain coalesced f32 stores (no atomics, no memset).
__global__ __launch_bounds__(128) void attn_kernel(
    const unsigned short* __restrict__ qkv, const unsigned short* __restrict__ Vt,
    float* __restrict__ out) {
  __shared__ __align__(16) unsigned short Ks[2][4224];
  __shared__ __align__(16) unsigned short Vs[2][4224];
  const int tid = threadIdx.x, lane = tid & 63, w = tid >> 6;   // w 0..1
  const int hiL = lane >> 5, li = lane & 31;
  const int bid = blockIdx.x;
  const int xcd = bid & 7, slot = bid >> 3;
  const int bh = xcd * 4 + (slot >> 4);          // XCD-pinned (b,h)
  const int j = slot & 15;
  const int b = bh >> 4, h = bh & 15;
  const int hi = 31 - j, lo = j;                 // 64-row tiles
  const size_t qbase = (size_t)(b * 2048) * 2048 + h * 64;
  const size_t kbase = qbase + 1024;
  const size_t vtbase = (size_t)(b * 1024 + h * 64) * 2048;

  // staging: thread -> row r_ (K: s, V: d), 4 chunks of 8 elems
  const int r_ = tid >> 1, half = tid & 1;
  const unsigned lwb = (unsigned)(((r_ >> 5) * 8 + half * 4) * 264 + (r_ & 31) * 8);
  const size_t kgb = kbase + (size_t)r_ * 2048 + half * 32;    // + st*64*2048
  const size_t vgb = vtbase + (size_t)r_ * 2048 + half * 32;   // + st*64

  int tile = hi, st = 0;
  int qrow0 = hi * 64 + w * 32;
  s16x8 qf0, qf1, qf2, qf3;
  {
    const unsigned short* qp = &qkv[qbase + (size_t)(qrow0 + li) * 2048 + hiL * 8];
    qf0 = *(const s16x8*)(qp);      qf1 = *(const s16x8*)(qp + 16);
    qf2 = *(const s16x8*)(qp + 32); qf3 = *(const s16x8*)(qp + 48);
  }
  f32x16 yacc0 = {}, yacc1 = {};

  // stage unit 0 (tile hi, st 0)
  s16x8 kr0, kr1, kr2, kr3, vr0, vr1, vr2, vr3;
  kr0 = *(const s16x8*)&qkv[kgb];      kr1 = *(const s16x8*)&qkv[kgb + 8];
  kr2 = *(const s16x8*)&qkv[kgb + 16]; kr3 = *(const s16x8*)&qkv[kgb + 24];
  vr0 = *(const s16x8*)&Vt[vgb];       vr1 = *(const s16x8*)&Vt[vgb + 8];
  vr2 = *(const s16x8*)&Vt[vgb + 16];  vr3 = *(const s16x8*)&Vt[vgb + 24];
  *(s16x8*)&Ks[0][lwb]           = kr0; *(s16x8*)&Ks[0][lwb + 264]     = kr1;
  *(s16x8*)&Ks[0][lwb + 2 * 264] = kr2; *(s16x8*)&Ks[0][lwb + 3 * 264] = kr3;
  *(s16x8*)&Vs[0][lwb]           = vr0; *(s16x8*)&Vs[0][lwb + 264]     = vr1;
  *(s16x8*)&Vs[0][lwb + 2 * 264] = vr2; *(s16x8*)&Vs[0][lwb + 3 * 264] = vr3;
  __syncthreads();

  int cur = 0;
  for (int i = 0; i < 33; ++i) {
    const bool pf = (i < 32);
    int tN, stN;
    if (i + 1 <= hi) { tN = hi; stN = i + 1; } else { tN = lo; stN = i - hi; }
    if (pf) {                                    // T14: issue next loads early
      const size_t ko = kgb + (size_t)stN * 64 * 2048;
      const size_t vo = vgb + stN * 64;
      kr0 = *(const s16x8*)&qkv[ko];      kr1 = *(const s16x8*)&qkv[ko + 8];
      kr2 = *(const s16x8*)&qkv[ko + 16]; kr3 = *(const s16x8*)&qkv[ko + 24];
      vr0 = *(const s16x8*)&Vt[vo];       vr1 = *(const s16x8*)&Vt[vo + 8];
      vr2 = *(const s16x8*)&Vt[vo + 16];  vr3 = *(const s16x8*)&Vt[vo + 24];
    }
    const int s0 = st * 64;
    const bool dm = (st == tile);                // diag step == last step of tile
    const unsigned short* Kc = Ks[cur];
    const unsigned short* Vc = Vs[cur];

    __builtin_amdgcn_s_setprio(1);
#pragma unroll
    for (int sb2 = 0; sb2 < 2; ++sb2) {
      f32x16 sacc = {};
      {
        const unsigned short* kp = &Kc[(sb2 * 8 + hiL) * 264 + li * 8];
        sacc = MFMA32(*(const s16x8*)(kp),           qf0, sacc);
        sacc = MFMA32(*(const s16x8*)(kp + 2 * 264), qf1, sacc);
        sacc = MFMA32(*(const s16x8*)(kp + 4 * 264), qf2, sacc);
        sacc = MFMA32(*(const s16x8*)(kp + 6 * 264), qf3, sacc);
      }
      float pr[16];
#pragma unroll
      for (int r = 0; r < 16; ++r) {
        float v = sacc[r] > 0.f ? sacc[r] : 0.f;
        if (dm) {
          const int sg = s0 + sb2 * 32 + (r & 3) + 8 * (r >> 2) + 4 * hiL;
          if (sg > qrow0 + li) v = 0.f;
        }
        pr[r] = v;
      }
#pragma unroll
      for (int hh = 0; hh < 2; ++hh) {
        u32 a0 = cvtpk1(pr[8 * hh + 0], pr[8 * hh + 1]);
        u32 b0 = cvtpk1(pr[8 * hh + 4], pr[8 * hh + 5]);
        u32 a1 = cvtpk1(pr[8 * hh + 2], pr[8 * hh + 3]);
        u32 b1 = cvtpk1(pr[8 * hh + 6], pr[8 * hh + 7]);
        pl32swap(a0, b0);
        pl32swap(a1, b1);
        union { s16x8 v; u32 wv[4]; } pa;
        pa.wv[0] = a0; pa.wv[1] = a1; pa.wv[2] = b0; pa.wv[3] = b1;
        const int sc = sb2 * 2 + hh;
        const unsigned short* vp = &Vc[(sc * 2 + hiL) * 264 + li * 8];
        yacc0 = MFMA32(pa.v, *(const s16x8*)(vp), yacc0);
        yacc1 = MFMA32(pa.v, *(const s16x8*)(vp + 8 * 264), yacc1);
      }
    }
    __builtin_amdgcn_s_setprio(0);

    if (pf) {                                    // write prefetched tile
      unsigned short* Kn = Ks[cur ^ 1];
      unsigned short* Vn = Vs[cur ^ 1];
      *(s16x8*)&Kn[lwb]           = kr0; *(s16x8*)&Kn[lwb + 264]     = kr1;
      *(s16x8*)&Kn[lwb + 2 * 264] = kr2; *(s16x8*)&Kn[lwb + 3 * 264] = kr3;
      *(s16x8*)&Vn[lwb]           = vr0; *(s16x8*)&Vn[lwb + 264]     = vr1;
      *(s16x8*)&Vn[lwb + 2 * 264] = vr2; *(s16x8*)&Vn[lwb + 3 * 264] = vr3;
    }

    if (dm) {                                    // end of this q-tile: store
      const size_t ob = (size_t)(b * 2048 + qrow0) * 1024 + h * 64 + li;
#pragma unroll
      for (int r = 0; r < 16; ++r) {
        const int ql = (r & 3) + 8 * (r >> 2) + 4 * hiL;
        out[ob + (size_t)ql * 1024]      = yacc0[r];
        out[ob + (size_t)ql * 1024 + 32] = yacc1[r];
      }
      if (pf) {                                  // switch to lo tile
        qrow0 = lo * 64 + w * 32;
        const unsigned short* qp = &qkv[qbase + (size_t)(qrow0 + li) * 2048 + hiL * 8];
        qf0 = *(const s16x8*)(qp);      qf1 = *(const s16x8*)(qp + 16);
        qf2 = *(const s16x8*)(qp + 32); qf3 = *(const s16x8*)(qp + 48);
        yacc0 = (f32x16){}; yacc1 = (f32x16){};
      }
    }
    __syncthreads();
    cur ^= 1; tile = tN; st = stN;
  }
}

extern "C" void kernel_launch(void* const* d_in, const int* in_sizes, int n_in,
                              void* d_out, int out_size, void* d_ws, size_t ws_size,
                              hipStream_t stream) {
  const float* x    = (const float*)d_in[0];
  const float* w    = (const float*)d_in[1];
  const float* bias = (const float*)d_in[2];
  float* out = (float*)d_out;

  unsigned short* xb  = (unsigned short*)d_ws;            // 4096*1024 elems
  unsigned short* wT  = xb  + (size_t)4096 * 1024;        // 3072*1024
  unsigned short* qkv = wT  + (size_t)3072 * 1024;        // 4096*2048 (q|k)
  unsigned short* Vt  = qkv + (size_t)4096 * 2048;        // 1024*2048*2 (v^T)

  cvt_x_kernel<<<4096, 256, 0, stream>>>(x, xb);
  transpose_w_kernel<<<dim3(48, 16), 256, 0, stream>>>(w, wT);
  gemm_qkv_kernel<<<768, 256, 0, stream>>>(xb, wT, bias, qkv, Vt);
  attn_kernel<<<512, 128, 0, stream>>>(qkv, Vt, out);
}

// Round 7
// 82.286 us; speedup vs baseline: 1.2659x; 1.1945x over previous
//
#include <hip/hip_runtime.h>

// Problem: B=2, T=2048, C=1024, H=16, D=64
// qkv = x @ w + b ; q,k,v split; att = relu(causal(q k^T / 8)); y = att @ v
// Output fp32 [B,T,C]. Compute in bf16 MFMA with fp32 accum.

typedef unsigned int u32;
typedef float  f32x4  __attribute__((ext_vector_type(4)));
typedef float  f32x16 __attribute__((ext_vector_type(16)));
typedef short  s16x8  __attribute__((ext_vector_type(8)));

#define MFMA_BF16(a, b, c) __builtin_amdgcn_mfma_f32_16x16x32_bf16((a), (b), (c), 0, 0, 0)
#define MFMA32(a, b, c)    __builtin_amdgcn_mfma_f32_32x32x16_bf16((a), (b), (c), 0, 0, 0)

#define GLOAD16(g, l)                                                        \
  __builtin_amdgcn_global_load_lds(                                          \
      (__attribute__((address_space(1))) void*)(g),                          \
      (__attribute__((address_space(3))) void*)(l), 16, 0, 0)

__device__ __forceinline__ unsigned short f2bf(float f) {
  union { float f; u32 u; } x; x.f = f;
  u32 r = (x.u + 0x7fffu + ((x.u >> 16) & 1u)) >> 16;
  return (unsigned short)r;
}

// HW packed f32->bf16 (round-to-nearest-even)
static __device__ __forceinline__ u32 cvtpk1(float a, float b) {
  u32 r;
  asm("v_cvt_pk_bf16_f32 %0, %1, %2" : "=v"(r) : "v"(a), "v"(b));
  return r;
}
// swap lanes[32:63] of a with lanes[0:31] of b
static __device__ __forceinline__ void pl32swap(u32& a, u32& b) {
  asm("v_permlane32_swap_b32 %0, %1" : "+v"(a), "+v"(b));
}

// ---------------- kernel 1: x fp32 -> bf16 ----------------
__global__ void cvt_x_kernel(const float* __restrict__ x, unsigned short* __restrict__ xb) {
  int i = blockIdx.x * 256 + threadIdx.x;
  float4 v = ((const float4*)x)[i];
  ushort4 o;
  o.x = f2bf(v.x); o.y = f2bf(v.y); o.z = f2bf(v.z); o.w = f2bf(v.w);
  ((ushort4*)xb)[i] = o;
}

// ---------------- kernel 2: w [1024][3072] fp32 -> wT [3072][1024] bf16 ----
__global__ void transpose_w_kernel(const float* __restrict__ w, unsigned short* __restrict__ wT) {
  __shared__ unsigned short TL[64][72];
  const int tid = threadIdx.x;
  const int c0 = blockIdx.x * 64;
  const int r0 = blockIdx.y * 64;
#pragma unroll
  for (int p = 0; p < 4; ++p) {
    int r = p * 16 + (tid >> 4);
    int c = (tid & 15) * 4;
    float4 v = *(const float4*)&w[(size_t)(r0 + r) * 3072 + c0 + c];
    TL[c + 0][r] = f2bf(v.x);
    TL[c + 1][r] = f2bf(v.y);
    TL[c + 2][r] = f2bf(v.z);
    TL[c + 3][r] = f2bf(v.w);
  }
  __syncthreads();
#pragma unroll
  for (int p = 0; p < 4; ++p) {
    int c = p * 16 + (tid >> 4);
    int r = (tid & 15) * 4;
    ushort4 o;
    o.x = TL[c][r + 0]; o.y = TL[c][r + 1]; o.z = TL[c][r + 2]; o.w = TL[c][r + 3];
    *(ushort4*)&wT[(size_t)(c0 + c) * 1024 + r0 + r] = o;
  }
}

// ---------------- kernel 3: GEMM qkv = xb @ wT^T + bias ------------------
// bn<8: q (pre-scaled 1/8) -> Cq[.][0:1024); bn in [8,16): k -> Cq[.][1024:2048)
// bn>=16: v transposed via LDS -> Vt [B][1024 d][T] with coalesced stores.
__global__ __launch_bounds__(256, 3) void gemm_qkv_kernel(
    const unsigned short* __restrict__ A, const unsigned short* __restrict__ Bt,
    const float* __restrict__ bias, unsigned short* __restrict__ Cq,
    unsigned short* __restrict__ Vt) {
  __shared__ __align__(16) unsigned short SM[8448];   // As | Bs, reused as TL
  unsigned short* As = SM;
  unsigned short* Bs = SM + 4096;
  const int tid = threadIdx.x;
  const int lane = tid & 63, wid = tid >> 6;
  const int wr = wid >> 1, wc = wid & 1;
  const int g = lane >> 4, lm = lane & 15;
  const int bid = blockIdx.x;
  const int xcd = bid & 7, wl = bid >> 3;              // wl 0..95
  const int bn = wl % 24;
  const int bm = xcd * 4 + wl / 24;

  const unsigned short* gA = A  + (size_t)(bm * 128 + wid * 32 + (lane >> 2)) * 1024 + (lane & 3) * 8;
  const unsigned short* gB = Bt + (size_t)(bn * 128 + wid * 32 + (lane >> 2)) * 1024 + (lane & 3) * 8;
  unsigned short* lA0 = &As[wid * 1024];
  unsigned short* lA1 = &As[wid * 1024 + 512];
  unsigned short* lB0 = &Bs[wid * 1024];
  unsigned short* lB1 = &Bs[wid * 1024 + 512];

  f32x4 acc[4][4] = {};

  for (int kt = 0; kt < 32; ++kt) {
    __syncthreads();
    const unsigned short* a0 = gA + kt * 32;
    const unsigned short* b0 = gB + kt * 32;
    GLOAD16(a0,             lA0);
    GLOAD16(a0 + 16 * 1024, lA1);
    GLOAD16(b0,             lB0);
    GLOAD16(b0 + 16 * 1024, lB1);
    __syncthreads();

    s16x8 af[4], bf[4];
#pragma unroll
    for (int m = 0; m < 4; ++m)
      af[m] = *(const s16x8*)&As[(wr * 64 + m * 16 + lm) * 32 + g * 8];
#pragma unroll
    for (int n = 0; n < 4; ++n)
      bf[n] = *(const s16x8*)&Bs[(wc * 64 + n * 16 + lm) * 32 + g * 8];
#pragma unroll
    for (int m = 0; m < 4; ++m)
#pragma unroll
      for (int n = 0; n < 4; ++n)
        acc[m][n] = MFMA_BF16(af[m], bf[n], acc[m][n]);
  }

  if (bn < 16) {
    const float qs = (bn < 8) ? 0.125f : 1.0f;   // fold attention scale into q
#pragma unroll
    for (int m = 0; m < 4; ++m) {
      const int row = bm * 128 + wr * 64 + m * 16 + g * 4;
#pragma unroll
      for (int n = 0; n < 4; ++n) {
        const int col = bn * 128 + wc * 64 + n * 16 + lm;
        const float bv = bias[col];
#pragma unroll
        for (int r = 0; r < 4; ++r)
          Cq[(size_t)(row + r) * 2048 + col] = f2bf((acc[m][n][r] + bv) * qs);
      }
    }
  } else {
    // V: transpose 128x128 C-tile via LDS (two 64-col passes), coalesced store
    unsigned short* TL = SM;                     // [64][132]
    const int bb = bm >> 4, tt0 = (bm & 15) * 128;
    __syncthreads();                             // As/Bs reads done
#pragma unroll
    for (int p = 0; p < 2; ++p) {
      if (wc == p) {
#pragma unroll
        for (int m = 0; m < 4; ++m) {
          const int r = wr * 64 + m * 16 + g * 4;
#pragma unroll
          for (int n = 0; n < 4; ++n) {
            const int c = n * 16 + lm;
            const float bv = bias[bn * 128 + p * 64 + c];
            ushort4 o;
#pragma unroll
            for (int r2 = 0; r2 < 4; ++r2)
              ((unsigned short*)&o)[r2] = f2bf(acc[m][n][r2] + bv);
            *(ushort4*)&TL[c * 132 + r] = o;
          }
        }
      }
      __syncthreads();
      const int cl = tid >> 2;                   // 0..63 local col
      const int ch = (tid & 3) * 32;
      const int cv = bn * 128 + p * 64 + cl - 2048;   // global d-row in Vt
      unsigned short* vrow = &Vt[((size_t)(bb * 1024 + cv)) * 2048 + tt0 + ch];
#pragma unroll
      for (int k2 = 0; k2 < 4; ++k2)
        *(s16x8*)&vrow[k2 * 8] = *(const s16x8*)&TL[cl * 132 + ch + k2 * 8];
      __syncthreads();
    }
  }
}

// ---------------- kernel 4: attention v7 (s-split warp pairs) -------------
// 256 blocks (32 bh x 8 j), 8 warps. Block owns 128-row groups (15-j, j)
// sequentially: 34 uniform KV steps. Warp (wt=w>>1, half=w&1) computes the
// 32 q-rows of tile wt but only s-half half*32..+31 of each 64-s step ->
// 8 KB LDS-read per warp-step, 2048 waves (8/CU). Partial yaccs merged
// pairwise via the just-consumed K/V LDS buffer at group end; plain stores.
__global__ __launch_bounds__(512, 2) void attn_kernel(
    const unsigned short* __restrict__ qkv, const unsigned short* __restrict__ Vt,
    float* __restrict__ out) {
  __shared__ __align__(16) unsigned short Ks[2][4224];
  __shared__ __align__(16) unsigned short Vs[2][4224];
  const int tid = threadIdx.x, lane = tid & 63, w = tid >> 6;   // w 0..7
  const int hiL = lane >> 5, li = lane & 31;
  const int wt = w >> 1, half = w & 1;
  const int bid = blockIdx.x;
  const int xcd = bid & 7, slot = bid >> 3;      // slot 0..31
  const int bh = xcd * 4 + (slot >> 3);          // XCD-pinned (b,h)
  const int j = slot & 7;
  const int b = bh >> 4, h = bh & 15;
  const int gA = 15 - j, gB = j;                 // 128-row groups
  const int nA = 2 * gA + 2;                     // steps in group A (34 total)
  const size_t qbase = (size_t)(b * 2048) * 2048 + h * 64;
  const size_t kbase = qbase + 1024;
  const size_t vtbase = (size_t)(b * 1024 + h * 64) * 2048;

  // staging: 512 thr -> row r_ (K: s, V: d), 8-elem chunk oct; frag-order LDS
  const int r_ = tid >> 3, oct = tid & 7;
  const unsigned lw = (unsigned)(((r_ >> 5) * 8 + oct) * 264 + (r_ & 31) * 8);
  const size_t kg0 = kbase + (size_t)r_ * 2048 + oct * 8;   // + st*64*2048
  const size_t vg0 = vtbase + (size_t)r_ * 2048 + oct * 8;  // + st*64

  int qrow0 = gA * 128 + wt * 32;
  s16x8 qf0, qf1, qf2, qf3;
  {
    const unsigned short* qp = &qkv[qbase + (size_t)(qrow0 + li) * 2048 + hiL * 8];
    qf0 = *(const s16x8*)(qp);      qf1 = *(const s16x8*)(qp + 16);
    qf2 = *(const s16x8*)(qp + 32); qf3 = *(const s16x8*)(qp + 48);
  }
  f32x16 yacc0 = {}, yacc1 = {};

  // prologue: stage tile 0 into buf0; prefetch tile 1 into regs
  s16x8 kr = *(const s16x8*)&qkv[kg0];
  s16x8 vr = *(const s16x8*)&Vt[vg0];
  *(s16x8*)&Ks[0][lw] = kr;
  *(s16x8*)&Vs[0][lw] = vr;
  kr = *(const s16x8*)&qkv[kg0 + (size_t)64 * 2048];
  vr = *(const s16x8*)&Vt[vg0 + 64];
  __syncthreads();

  int cur = 0;
  for (int u = 0; u < 34; ++u) {
    const int g  = (u < nA) ? gA : gB;
    const int st = (u < nA) ? u : u - nA;
    // (a) write prefetched tile u+1 (safe: buf last read at step u-1)
    if (u + 1 < 34) {
      *(s16x8*)&Ks[cur ^ 1][lw] = kr;
      *(s16x8*)&Vs[cur ^ 1][lw] = vr;
    }
    // (b) issue global loads for tile u+2 (2-step-deep prefetch)
    if (u + 2 < 34) {
      const int s2 = (u + 2 < nA) ? (u + 2) : (u + 2 - nA);
      kr = *(const s16x8*)&qkv[kg0 + (size_t)s2 * 64 * 2048];
      vr = *(const s16x8*)&Vt[vg0 + s2 * 64];
    }
    // (c) compute (s-half of this step)
    const int sEff = st * 64 + half * 32;
    if (sEff <= qrow0 + 31) {
      const bool dm = (sEff + 31 > qrow0);       // diag crosses this half
      const unsigned short* Kc = Ks[cur];
      const unsigned short* Vc = Vs[cur];
      __builtin_amdgcn_s_setprio(1);
      f32x16 sacc = {};
      {
        const unsigned short* kp = &Kc[(half * 8 + hiL) * 264 + li * 8];
        sacc = MFMA32(*(const s16x8*)(kp),           qf0, sacc);
        sacc = MFMA32(*(const s16x8*)(kp + 2 * 264), qf1, sacc);
        sacc = MFMA32(*(const s16x8*)(kp + 4 * 264), qf2, sacc);
        sacc = MFMA32(*(const s16x8*)(kp + 6 * 264), qf3, sacc);
      }
      float pr[16];
#pragma unroll
      for (int r = 0; r < 16; ++r) {
        float v = sacc[r] > 0.f ? sacc[r] : 0.f;
        if (dm) {
          const int sg = sEff + (r & 3) + 8 * (r >> 2) + 4 * hiL;
          if (sg > qrow0 + li) v = 0.f;
        }
        pr[r] = v;
      }
#pragma unroll
      for (int hh = 0; hh < 2; ++hh) {
        u32 a0 = cvtpk1(pr[8 * hh + 0], pr[8 * hh + 1]);
        u32 b0 = cvtpk1(pr[8 * hh + 4], pr[8 * hh + 5]);
        u32 a1 = cvtpk1(pr[8 * hh + 2], pr[8 * hh + 3]);
        u32 b1 = cvtpk1(pr[8 * hh + 6], pr[8 * hh + 7]);
        pl32swap(a0, b0);
        pl32swap(a1, b1);
        union { s16x8 v; u32 wv[4]; } pa;
        pa.wv[0] = a0; pa.wv[1] = a1; pa.wv[2] = b0; pa.wv[3] = b1;
        const int sc = half * 2 + hh;            // s 16-block index
        const unsigned short* vp = &Vc[(sc * 2 + hiL) * 264 + li * 8];
        yacc0 = MFMA32(pa.v, *(const s16x8*)(vp), yacc0);
        yacc1 = MFMA32(pa.v, *(const s16x8*)(vp + 8 * 264), yacc1);
      }
      __builtin_amdgcn_s_setprio(0);
    }
    // (d) group end: merge s-halves via LDS (reuse consumed buf), store
    if (st == 2 * g + 1) {
      __syncthreads();                           // all reads of Ks/Vs[cur] done
      float* M0 = (float*)&Ks[cur][0];           // 8 KB scratch (tile slot 0)
      float* M1 = (float*)&Vs[cur][0];           // 8 KB scratch (tile slot 1)
#pragma unroll
      for (int ph = 0; ph < 2; ++ph) {
        const bool my = ((wt >> 1) == ph);
        float* M = (wt & 1) ? M1 : M0;
        if (my && half == 0) {
#pragma unroll
          for (int r = 0; r < 16; ++r) {
            const int ql = (r & 3) + 8 * (r >> 2) + 4 * hiL;
            M[ql * 64 + li]      = yacc0[r];
            M[ql * 64 + li + 32] = yacc1[r];
          }
        }
        __syncthreads();
        if (my && half == 1) {
          const size_t ob = (size_t)(b * 2048 + qrow0) * 1024 + h * 64 + li;
#pragma unroll
          for (int r = 0; r < 16; ++r) {
            const int ql = (r & 3) + 8 * (r >> 2) + 4 * hiL;
            out[ob + (size_t)ql * 1024]      = yacc0[r] + M[ql * 64 + li];
            out[ob + (size_t)ql * 1024 + 32] = yacc1[r] + M[ql * 64 + li + 32];
          }
        }
        __syncthreads();
      }
      if (u + 1 < 34) {                          // switch to group B
        qrow0 = gB * 128 + wt * 32;
        const unsigned short* qp = &qkv[qbase + (size_t)(qrow0 + li) * 2048 + hiL * 8];
        qf0 = *(const s16x8*)(qp);      qf1 = *(const s16x8*)(qp + 16);
        qf2 = *(const s16x8*)(qp + 32); qf3 = *(const s16x8*)(qp + 48);
        yacc0 = (f32x16){}; yacc1 = (f32x16){};
      }
    }
    __syncthreads();
    cur ^= 1;
  }
}

extern "C" void kernel_launch(void* const* d_in, const int* in_sizes, int n_in,
                              void* d_out, int out_size, void* d_ws, size_t ws_size,
                              hipStream_t stream) {
  const float* x    = (const float*)d_in[0];
  const float* w    = (const float*)d_in[1];
  const float* bias = (const float*)d_in[2];
  float* out = (float*)d_out;

  unsigned short* xb  = (unsigned short*)d_ws;            // 4096*1024 elems
  unsigned short* wT  = xb  + (size_t)4096 * 1024;        // 3072*1024
  unsigned short* qkv = wT  + (size_t)3072 * 1024;        // 4096*2048 (q|k)
  unsigned short* Vt  = qkv + (size_t)4096 * 2048;        // 1024*2048*2 (v^T)

  cvt_x_kernel<<<4096, 256, 0, stream>>>(x, xb);
  transpose_w_kernel<<<dim3(48, 16), 256, 0, stream>>>(w, wT);
  gemm_qkv_kernel<<<768, 256, 0, stream>>>(xb, wT, bias, qkv, Vt);
  attn_kernel<<<256, 512, 0, stream>>>(qkv, Vt, out);
}